// Round 8
// baseline (213.214 us; speedup 1.0000x reference)
//
#include <hip/hip_runtime.h>

// LSTM B=8192, T=168, P=16, H=24, gates [i,f,g,o].
// Round-16b: (resubmit after infra failure; identical content)
// Pade-rational activations + lgkmcnt-only step barrier.
//  - r15 post-mortem: stagger = EXACT zero; r10(2w/SIMD)=r12(4w/SIMD)=1405
//    cyc/step -> step is intrinsic serial chain, issue hides inside it.
//    Chain ~= barrier(100) + ds_read B1(150) + MFMA(60-150) + ACT(450-600:
//    5 dependent ~100cyc trans + lockstep trans-issue pileup) + write(50).
//  - Fix A: tanh Pade[7/6]: tanh(y)=y*N(u)/D(u), u=y^2, |y|<=5 clamp
//    (err ~1e-4). N=((u+378)u+17325)u+135135; D=((28u+3150)u+62370)u+135135.
//    sigma(x)=(D+yN)/(2D), y=x/2. Shared denominators:
//      c' = [Af*c*Di*Dg + Ai*(yg*Ng)*Df] * rcp(2*Df*Di*Dg)
//      h  = Ao*(yc*Nc) * rcp(2*Do*Dc),  yc=clamp(c',5)
//    => 2 trans/cell (was 7), act chain trans-latency 5x100 -> 2x110,
//    rest full-rate FMA. Per-SIMD trans issue 448 -> 128.
//  - Fix B: in-loop barrier = s_waitcnt lgkmcnt(0); s_barrier (no vmcnt
//    drain of __syncthreads). Staging keeps __syncthreads.
//  - Everything else identical to r12 (98us): 8 waves x 1 tile, self-
//    aligned exchange (write hx[q][n][w] b16, read half8 b128), LDS
//    x-staging with +24 f16/batch pad.

#define T_STEPS 168
#define P_FEAT  16
#define TCH     84                 // t-chunk length (2 chunks)
#define NB      16                 // batches per block
#define BPAD    24                 // f16 pad per batch (2-way banks)
#define BSTR    (TCH * 16 + BPAD)  // 1368 f16 per batch

typedef _Float16 half8 __attribute__((ext_vector_type(8)));
typedef _Float16 h2    __attribute__((ext_vector_type(2)));
typedef float    f32x4 __attribute__((ext_vector_type(4)));

__device__ __forceinline__ float rcp_fast(float x) {
#if __has_builtin(__builtin_amdgcn_rcpf)
    return __builtin_amdgcn_rcpf(x);
#else
    return 1.0f / x;
#endif
}
__device__ __forceinline__ float exp2_fast(float x) {
#if __has_builtin(__builtin_amdgcn_exp2f)
    return __builtin_amdgcn_exp2f(x);
#else
    return exp2f(x);
#endif
}
__device__ __forceinline__ float tanh_f(float x) {   // epilogue only
    return 1.0f - 2.0f * rcp_fast(1.0f + exp2_fast(x * 2.88539008f));
}
__device__ __forceinline__ h2 pack2(float a, float b) {
    h2 r; r.x = (_Float16)a; r.y = (_Float16)b; return r;
}
// Pade[7/6] tanh numerator/denominator polys in u = y^2 (|y| <= 5)
__device__ __forceinline__ float padeN(float u) {
    return fmaf(fmaf(u + 378.0f, u, 17325.0f), u, 135135.0f);
}
__device__ __forceinline__ float padeD(float u) {
    return fmaf(fmaf(fmaf(28.0f, u, 3150.0f), u, 62370.0f), u, 135135.0f);
}
__device__ __forceinline__ float clamp5(float x) {
    return fminf(fmaxf(x, -5.0f), 5.0f);
}
// lgkmcnt(0) + s_barrier, WITHOUT the vmcnt(0) drain __syncthreads adds.
__device__ __forceinline__ void soft_barrier() {
    asm volatile("s_waitcnt lgkmcnt(0)\n\ts_barrier" ::: "memory");
}

__global__ __launch_bounds__(512, 4) void lstm_8w(
    const float* __restrict__ x,
    const float* __restrict__ W_ih,
    const float* __restrict__ W_hh,
    const float* __restrict__ b_ih,
    const float* __restrict__ b_hh,
    const float* __restrict__ W_lin,
    const float* __restrict__ b_lin,
    float* __restrict__ out)
{
    __shared__ __align__(16) _Float16 xs16[NB * BSTR];     // 43776 B (W-stage reused)
    __shared__ __align__(16) _Float16 hx[2][4][NB][8];     //  2048 B ping-pong h
    __shared__ __align__(16) _Float16 zblk[16];            //    32 B zeros (B2 pad)
    __shared__ __align__(16) float    thbuf[NB][24];       //  1536 B epilogue

    const int tid  = threadIdx.x;
    const int w    = tid >> 6;       // wave 0..7: tile mt = w
    const int lane = tid & 63;
    const int n    = lane & 15;      // batch col (B/C) == row p supplied (A)
    const int q    = lane >> 4;      // k-chunk (A/B) == output quad (C)

    // ---- one-time: stage fused W (f32) into xs16 space ----
    float* wstage = reinterpret_cast<float*>(xs16);        // 96*40 f32
    for (int idx = tid; idx < 96 * 40; idx += 512) {
        const int j = idx / 40;
        const int k = idx - j * 40;
        wstage[idx] = (k < 24) ? W_hh[j * 24 + k] : W_ih[j * 16 + (k - 24)];
    }
    __syncthreads();

    // ---- A-fragments for this wave's tile (mt = w) ----
    // tile row p: gate p%4 of unit 8*(p/4)+mt; rows p>=12 zero.
    half8 A1, A2;
    f32x4 biasf;
    {
        const int mt = w;
        const int p  = n;
        const bool vrow = (p < 12);
        const int grow = vrow ? ((p & 3) * 24 + 8 * (p >> 2) + mt) : 0;
        #pragma unroll
        for (int j = 0; j < 8; j++) {
            const int k = q * 8 + j;
            A1[j] = (vrow && k < 24) ? (_Float16)wstage[grow * 40 + k]      : (_Float16)0.0f;
            A2[j] = (vrow && k < 16) ? (_Float16)wstage[grow * 40 + 24 + k] : (_Float16)0.0f;
        }
        #pragma unroll
        for (int r = 0; r < 4; r++) {
            const int u = 8 * q + mt;   // lane (q,n) holds gates r of unit u (q<3)
            biasf[r] = (q < 3) ? (b_ih[r * 24 + u] + b_hh[r * 24 + u]) : 0.0f;
        }
    }
    // zero hx (both buffers; q=3 rows stay 0 forever = k-pad) + zblk
    {
        unsigned* hz = reinterpret_cast<unsigned*>(&hx[0][0][0][0]);  // 512 dwords
        for (int i = tid; i < 512; i += 512) hz[i] = 0u;
        if (tid < 8) reinterpret_cast<unsigned*>(zblk)[tid] = 0u;
    }
    __syncthreads();   // wstage dead; x staging reuses the space

    float c  = 0.0f;
    float hv = 0.0f;

    const float4* xsrc = reinterpret_cast<const float4*>(x)
                       + (size_t)(blockIdx.x * NB) * (T_STEPS * P_FEAT / 4);

    // B2 source: quads 0..1 read x halves, quads 2..3 the zero block
    const _Float16* xrowbase = (q < 2) ? &xs16[n * BSTR + q * 8] : zblk;
    const int xstep = (q < 2) ? 16 : 0;

    int bufp = 0;
    for (int ch = 0; ch < 2; ch++) {
        // stage NB x TCH x 16 f32 -> f16 (padded layout): 5376 float4
        for (int i = 0; i < 11; i++) {
            const int m = tid + 512 * i;        // 0..5375
            if (m < 5376) {
                const int b   = m / 336;        // 336 float4 per batch-chunk
                const int rem = m - b * 336;
                const float4 v = xsrc[(size_t)b * 672 + ch * 336 + rem];
                h2* dst = reinterpret_cast<h2*>(xs16) + b * (BSTR / 2) + rem * 2;
                dst[0] = pack2(v.x, v.y);
                dst[1] = pack2(v.z, v.w);
            }
        }
        __syncthreads();

        // gx prologue for t=0 of this chunk
        f32x4 gx;
        {
            const half8 B2 = *reinterpret_cast<const half8*>(xrowbase);
            gx = __builtin_amdgcn_mfma_f32_16x16x32_f16(A2, B2, biasf, 0, 0, 0);
        }

        for (int t = 0; t < TCH; t++) {
            // B1: element j = h of unit 8q+j for batch n (j=w written by wave w)
            const half8 B1 = *reinterpret_cast<const half8*>(&hx[bufp][q][n][0]);
            // prefetch next step's x fragment (last iter: dummy index 0)
            const int tn = (t + 1 < TCH) ? t + 1 : 0;
            const half8 B2n = *reinterpret_cast<const half8*>(xrowbase + tn * xstep);

            f32x4 g = __builtin_amdgcn_mfma_f32_16x16x32_f16(A1, B1, gx, 0, 0, 0);
            gx = __builtin_amdgcn_mfma_f32_16x16x32_f16(A2, B2n, biasf, 0, 0, 0);

            // Pade-rational activations: 2 rcp + ~60 FMA-class ops
            {
                const float yi = clamp5(0.5f * g[0]);    // i-gate, y = x/2
                const float yf = clamp5(0.5f * g[1]);    // f-gate
                const float yg = clamp5(g[2]);           // g-gate (tanh direct)
                const float yo = clamp5(0.5f * g[3]);    // o-gate
                const float ui = yi * yi, uf = yf * yf, ug = yg * yg, uo = yo * yo;
                const float Ni = padeN(ui), Di = padeD(ui);
                const float Nf = padeN(uf), Df = padeD(uf);
                const float Ng = padeN(ug), Dg = padeD(ug);
                const float No = padeN(uo), Do = padeD(uo);
                const float Ai = fmaf(yi, Ni, Di);       // 2Di*sigmoid(gi)
                const float Af = fmaf(yf, Nf, Df);
                const float Ao = fmaf(yo, No, Do);
                const float Bg = yg * Ng;                // Dg*tanh(gg)
                const float t2 = Di * Dg;
                const float p1 = (Af * c) * t2;
                const float p2 = Ai * Bg;
                const float num = fmaf(p2, Df, p1);
                const float den = t2 * Df;
                const float cn  = num * rcp_fast(den + den);
                c = cn;
                const float yc = clamp5(cn);
                const float uc = yc * yc;
                const float Nc = padeN(uc), Dc = padeD(uc);
                const float numh = Ao * (yc * Nc);
                const float denh = Do * Dc;
                hv = numh * rcp_fast(denh + denh);
            }

            // publish own unit to the other buffer; q=3 stays zero (k-pad)
            if (q < 3) hx[1 - bufp][q][n][w] = (_Float16)hv;
            bufp ^= 1;
            soft_barrier();
        }
    }

    // ---- epilogue: out[b][u] = b_lin[u] + sum_k tanh(h[k]) * W_lin[u][k] ----
    if (q < 3) thbuf[n][8 * q + w] = tanh_f(hv);
    __syncthreads();

    if (q < 3) {
        const int batch = blockIdx.x * NB + n;
        const int u = 8 * q + w;
        const float* wl = &W_lin[u * 24];
        float acc = b_lin[u];
        #pragma unroll
        for (int k = 0; k < 24; k++) acc = fmaf(thbuf[n][k], wl[k], acc);
        out[(size_t)batch * 24 + u] = acc;
    }
}

extern "C" void kernel_launch(void* const* d_in, const int* in_sizes, int n_in,
                              void* d_out, int out_size, void* d_ws, size_t ws_size,
                              hipStream_t stream) {
    const float* x     = (const float*)d_in[0];
    const float* W_ih  = (const float*)d_in[1];
    const float* W_hh  = (const float*)d_in[2];
    const float* b_ih  = (const float*)d_in[3];
    const float* b_hh  = (const float*)d_in[4];
    const float* W_lin = (const float*)d_in[5];
    const float* b_lin = (const float*)d_in[6];
    float* out = (float*)d_out;

    const int B = in_sizes[0] / (T_STEPS * P_FEAT);   // 8192
    dim3 grid(B / NB), block(512);                    // 512 blocks x 8 waves
    lstm_8w<<<grid, block, 0, stream>>>(x, W_ih, W_hh, b_ih, b_hh, W_lin, b_lin, out);
}